// Round 1
// baseline (731.546 us; speedup 1.0000x reference)
//
#include <hip/hip_runtime.h>
#include <cstdint>
#include <cstddef>

#define BATCH 32
#define HWDIM 1024
#define MROWS 32768   // BATCH*HWDIM
#define CDIM  1024    // feature dim
#define NCL   1024    // clusters

typedef __attribute__((ext_vector_type(8))) short bf16x8;
typedef __attribute__((ext_vector_type(4))) float f32x4;
typedef __attribute__((ext_vector_type(8))) unsigned short u16x8;
typedef __attribute__((ext_vector_type(4))) unsigned short u16x4;

// ---------- helpers ----------
__device__ __forceinline__ unsigned short f2bf(float f) {
  unsigned u = __float_as_uint(f);
  unsigned r = u + 0x7fffu + ((u >> 16) & 1u);   // round-to-nearest-even
  return (unsigned short)(r >> 16);
}
__device__ __forceinline__ float bf2f(unsigned short h) {
  return __uint_as_float(((unsigned)h) << 16);
}
// order-preserving float->uint key for atomicMax on floats
__device__ __forceinline__ unsigned fkey(float f) {
  unsigned u = __float_as_uint(f);
  return (u & 0x80000000u) ? ~u : (u | 0x80000000u);
}
__device__ __forceinline__ float funkey(unsigned k) {
  unsigned u = (k & 0x80000000u) ? (k & 0x7fffffffu) : ~k;
  return __uint_as_float(u);
}
__device__ __forceinline__ void async16(const unsigned short* g, unsigned short* l) {
  __builtin_amdgcn_global_load_lds(
      (const __attribute__((address_space(1))) unsigned int*)g,
      (__attribute__((address_space(3))) unsigned int*)l, 16, 0, 0);
}
__device__ __forceinline__ f32x4 mfma16(bf16x8 a, bf16x8 b, f32x4 c) {
  return __builtin_amdgcn_mfma_f32_16x16x32_bf16(a, b, c, 0, 0, 0);
}

// ---------- 1) normalize x rows, emit split-bf16 ----------
__global__ __launch_bounds__(256) void normx_kernel(
    const float* __restrict__ x, unsigned short* __restrict__ Ahi,
    unsigned short* __restrict__ Alo) {
  const int row = blockIdx.x;
  const int t = threadIdx.x;
  const float4 v = *(const float4*)(x + (size_t)row * CDIM + t * 4);
  float ss = v.x * v.x + v.y * v.y + v.z * v.z + v.w * v.w;
  for (int o = 32; o > 0; o >>= 1) ss += __shfl_xor(ss, o);
  __shared__ float red[4];
  const int wave = t >> 6, lane = t & 63;
  if (lane == 0) red[wave] = ss;
  __syncthreads();
  const float tot = red[0] + red[1] + red[2] + red[3];
  const float inv = 1.0f / fmaxf(sqrtf(tot), 1e-7f);
  float f0 = v.x * inv, f1 = v.y * inv, f2 = v.z * inv, f3 = v.w * inv;
  u16x4 hi, lo;
  hi[0] = f2bf(f0); lo[0] = f2bf(f0 - bf2f(hi[0]));
  hi[1] = f2bf(f1); lo[1] = f2bf(f1 - bf2f(hi[1]));
  hi[2] = f2bf(f2); lo[2] = f2bf(f2 - bf2f(hi[2]));
  hi[3] = f2bf(f3); lo[3] = f2bf(f3 - bf2f(hi[3]));
  *(u16x4*)(Ahi + (size_t)row * CDIM + t * 4) = hi;
  *(u16x4*)(Alo + (size_t)row * CDIM + t * 4) = lo;
}

// ---------- 2) split W into bf16 hi/lo ----------
__global__ __launch_bounds__(256) void convw_kernel(
    const float* __restrict__ Wm, unsigned short* __restrict__ Bhi,
    unsigned short* __restrict__ Blo) {
  const int row = blockIdx.x;
  const int t = threadIdx.x;
  const float4 v = *(const float4*)(Wm + (size_t)row * CDIM + t * 4);
  u16x4 hi, lo;
  hi[0] = f2bf(v.x); lo[0] = f2bf(v.x - bf2f(hi[0]));
  hi[1] = f2bf(v.y); lo[1] = f2bf(v.y - bf2f(hi[1]));
  hi[2] = f2bf(v.z); lo[2] = f2bf(v.z - bf2f(hi[2]));
  hi[3] = f2bf(v.w); lo[3] = f2bf(v.w - bf2f(hi[3]));
  *(u16x4*)(Bhi + (size_t)row * CDIM + t * 4) = hi;
  *(u16x4*)(Blo + (size_t)row * CDIM + t * 4) = lo;
}

// ---------- 3) split-bf16 GEMM: C[m][n] = sum_c A[m][c]*B[n][c] ----------
// 128x128 tile, BK=32, 3 MFMAs (hh + hl + lh), single fp32 accumulator.
__global__ __launch_bounds__(256, 2) void gemm_kernel(
    const unsigned short* __restrict__ Ahi, const unsigned short* __restrict__ Alo,
    const unsigned short* __restrict__ Bhi, const unsigned short* __restrict__ Blo,
    float* __restrict__ C) {
  __shared__ unsigned short sAhi[128 * 32], sAlo[128 * 32];
  __shared__ unsigned short sBhi[128 * 32], sBlo[128 * 32];
  const int n0 = blockIdx.x * 128;
  const int m0 = blockIdx.y * 128;
  const int tid = threadIdx.x;
  const int wave = tid >> 6;
  const int lane = tid & 63;
  const int fl = lane & 15;   // fragment row/col
  const int q = lane >> 4;    // quad: k-offset q*8 (inputs), row-offset q*4 (C/D)
  const int wr = (wave >> 1) * 64;
  const int wc = (wave & 1) * 64;

  f32x4 acc[4][4];
#pragma unroll
  for (int i = 0; i < 4; i++)
#pragma unroll
    for (int j = 0; j < 4; j++) { f32x4 z = {0.f, 0.f, 0.f, 0.f}; acc[i][j] = z; }

  const int srow = lane >> 2;        // row within 16-row chunk
  const int skk = (lane & 3) * 8;    // k element offset within 32

  for (int k0 = 0; k0 < CDIM; k0 += 32) {
    __syncthreads();  // prior iteration's LDS reads complete
#pragma unroll
    for (int c = 0; c < 2; ++c) {
      const int chunk = wave * 2 + c;          // 0..7, wave-uniform
      const int r = chunk * 16 + srow;
      const size_t ga = (size_t)(m0 + r) * CDIM + k0 + skk;
      const size_t gb = (size_t)(n0 + r) * CDIM + k0 + skk;
      async16(Ahi + ga, &sAhi[chunk * 512]);
      async16(Alo + ga, &sAlo[chunk * 512]);
      async16(Bhi + gb, &sBhi[chunk * 512]);
      async16(Blo + gb, &sBlo[chunk * 512]);
    }
    __syncthreads();  // vmcnt(0) drain lands the async copies

    bf16x8 ah[4], al[4], bh[4], bl[4];
#pragma unroll
    for (int i = 0; i < 4; i++) {
      ah[i] = *(const bf16x8*)&sAhi[(wr + i * 16 + fl) * 32 + q * 8];
      al[i] = *(const bf16x8*)&sAlo[(wr + i * 16 + fl) * 32 + q * 8];
      bh[i] = *(const bf16x8*)&sBhi[(wc + i * 16 + fl) * 32 + q * 8];
      bl[i] = *(const bf16x8*)&sBlo[(wc + i * 16 + fl) * 32 + q * 8];
    }
#pragma unroll
    for (int i = 0; i < 4; i++)
#pragma unroll
      for (int j = 0; j < 4; j++) {
        acc[i][j] = mfma16(ah[i], bh[j], acc[i][j]);
        acc[i][j] = mfma16(ah[i], bl[j], acc[i][j]);
        acc[i][j] = mfma16(al[i], bh[j], acc[i][j]);
      }
  }

  // epilogue: C/D layout col=lane&15, row=q*4+reg
#pragma unroll
  for (int i = 0; i < 4; i++)
#pragma unroll
    for (int j = 0; j < 4; j++)
#pragma unroll
      for (int r = 0; r < 4; r++) {
        const int gm = m0 + wr + i * 16 + q * 4 + r;
        const int gn = n0 + wc + j * 16 + fl;
        C[(size_t)gm * NCL + gn] = acc[i][j][r];
      }
}

// ---------- 4) column max of logits per (batch, k) ----------
__global__ __launch_bounds__(256) void colmax_kernel(
    const float* __restrict__ L, unsigned* __restrict__ sk) {
  const int b = blockIdx.x >> 2, ch = blockIdx.x & 3, t = threadIdx.x;
  const float* p = L + ((size_t)b * HWDIM + ch * 256) * NCL + t * 4;
  float m0 = -3.4e38f, m1 = m0, m2 = m0, m3 = m0;
  for (int r = 0; r < 256; ++r) {
    float4 v = *(const float4*)(p + (size_t)r * NCL);
    m0 = fmaxf(m0, v.x); m1 = fmaxf(m1, v.y);
    m2 = fmaxf(m2, v.z); m3 = fmaxf(m3, v.w);
  }
  unsigned* d = sk + b * NCL + t * 4;
  atomicMax(d + 0, fkey(m0)); atomicMax(d + 1, fkey(m1));
  atomicMax(d + 2, fkey(m2)); atomicMax(d + 3, fkey(m3));
}

// ---------- 5) E = exp(l/0.06 + 50 - shift) -> bf16; S1 = colsum(E) ----------
__global__ __launch_bounds__(256) void expcs_kernel(
    const float* __restrict__ L, const unsigned* __restrict__ sk,
    unsigned short* __restrict__ E, float* __restrict__ S1) {
  const int b = blockIdx.x >> 2, ch = blockIdx.x & 3, t = threadIdx.x;
  const size_t base = ((size_t)b * HWDIM + ch * 256) * NCL + t * 4;
  const unsigned* kp = sk + b * NCL + t * 4;
  const float o0 = 50.f - funkey(kp[0]) / 0.06f;
  const float o1 = 50.f - funkey(kp[1]) / 0.06f;
  const float o2 = 50.f - funkey(kp[2]) / 0.06f;
  const float o3 = 50.f - funkey(kp[3]) / 0.06f;
  float s0 = 0, s1 = 0, s2 = 0, s3 = 0;
  for (int r = 0; r < 256; ++r) {
    float4 v = *(const float4*)(L + base + (size_t)r * NCL);
    float e0 = expf(v.x / 0.06f + o0);
    float e1 = expf(v.y / 0.06f + o1);
    float e2 = expf(v.z / 0.06f + o2);
    float e3 = expf(v.w / 0.06f + o3);
    s0 += e0; s1 += e1; s2 += e2; s3 += e3;
    u16x4 ev; ev[0] = f2bf(e0); ev[1] = f2bf(e1); ev[2] = f2bf(e2); ev[3] = f2bf(e3);
    *(u16x4*)(E + base + (size_t)r * NCL) = ev;
  }
  float* d = S1 + b * NCL + t * 4;
  atomicAdd(d + 0, s0); atomicAdd(d + 1, s1);
  atomicAdd(d + 2, s2); atomicAdd(d + 3, s3);
}

// ---------- 6) row sums T[n] = sum_k E[n,k] * c[k]; c chained from S1..S_nS ----------
__global__ __launch_bounds__(256) void rowsum_kernel(
    const unsigned short* __restrict__ E, const float* __restrict__ S1,
    const float* __restrict__ S2, const float* __restrict__ S3, int nS,
    float* __restrict__ Tout) {
  __shared__ float cs[NCL];
  const int b = blockIdx.x >> 4, rc = blockIdx.x & 15, t = threadIdx.x;
  {
    const int k = t * 4;
    float4 s1 = *(const float4*)(S1 + b * NCL + k);
    float c0 = 1.f / (s1.x + 1e-8f), c1 = 1.f / (s1.y + 1e-8f);
    float c2 = 1.f / (s1.z + 1e-8f), c3 = 1.f / (s1.w + 1e-8f);
    if (nS >= 2) {
      float4 s2 = *(const float4*)(S2 + b * NCL + k);
      c0 = c0 / (c0 * s2.x + 1e-8f); c1 = c1 / (c1 * s2.y + 1e-8f);
      c2 = c2 / (c2 * s2.z + 1e-8f); c3 = c3 / (c3 * s2.w + 1e-8f);
    }
    if (nS >= 3) {
      float4 s3 = *(const float4*)(S3 + b * NCL + k);
      c0 = c0 / (c0 * s3.x + 1e-8f); c1 = c1 / (c1 * s3.y + 1e-8f);
      c2 = c2 / (c2 * s3.z + 1e-8f); c3 = c3 / (c3 * s3.w + 1e-8f);
    }
    cs[k] = c0; cs[k + 1] = c1; cs[k + 2] = c2; cs[k + 3] = c3;
  }
  __syncthreads();
  const int wave = t >> 6, lane = t & 63;
  for (int rr = wave; rr < 64; rr += 4) {
    const int row = b * HWDIM + rc * 64 + rr;
    const unsigned short* ep = E + (size_t)row * NCL + lane * 16;
    u16x8 e0 = *(const u16x8*)ep;
    u16x8 e1 = *(const u16x8*)(ep + 8);
    const float* cp = cs + lane * 16;
    float sum = 0.f;
#pragma unroll
    for (int j = 0; j < 8; j++) sum += bf2f(e0[j]) * cp[j];
#pragma unroll
    for (int j = 0; j < 8; j++) sum += bf2f(e1[j]) * cp[8 + j];
    for (int o = 32; o > 0; o >>= 1) sum += __shfl_xor(sum, o);
    if (lane == 0) Tout[row] = sum;
  }
}

// ---------- 7) col sums S[b,k] = sum_n E[n,k] * r[n]; r chained from T1..T_nT ----------
__global__ __launch_bounds__(256) void colsum_kernel(
    const unsigned short* __restrict__ E, const float* __restrict__ T1,
    const float* __restrict__ T2, const float* __restrict__ T3, int nT,
    float* __restrict__ Sout) {
  __shared__ float rs[256];
  const int b = blockIdx.x >> 2, ch = blockIdx.x & 3, t = threadIdx.x;
  const int row0 = b * HWDIM + ch * 256;
  {
    float r = 1.f / (T1[row0 + t] + 1e-8f);
    if (nT >= 2) r = r / (r * T2[row0 + t] + 1e-8f);
    if (nT >= 3) r = r / (r * T3[row0 + t] + 1e-8f);
    rs[t] = r;
  }
  __syncthreads();
  float a0 = 0, a1 = 0, a2 = 0, a3 = 0;
  const unsigned short* base = E + (size_t)row0 * NCL + t * 4;
  for (int r = 0; r < 256; ++r) {
    const float rv = rs[r];
    u16x4 ev = *(const u16x4*)(base + (size_t)r * NCL);
    a0 += bf2f(ev[0]) * rv; a1 += bf2f(ev[1]) * rv;
    a2 += bf2f(ev[2]) * rv; a3 += bf2f(ev[3]) * rv;
  }
  float* d = Sout + b * NCL + t * 4;
  atomicAdd(d + 0, a0); atomicAdd(d + 1, a1);
  atomicAdd(d + 2, a2); atomicAdd(d + 3, a3);
}

// ---------- 8) final: assignments (in-place over logits) + loss ----------
__global__ __launch_bounds__(256) void final_kernel(
    float* __restrict__ IO, const unsigned* __restrict__ sk,
    const float* __restrict__ S1, const float* __restrict__ S2,
    const float* __restrict__ S3, const float* __restrict__ T1,
    const float* __restrict__ T2, const float* __restrict__ T3,
    float* __restrict__ lossout) {
  __shared__ float cs[NCL];
  __shared__ float offs[NCL];
  __shared__ float lred[4];
  const int b = blockIdx.x >> 4, rc = blockIdx.x & 15, t = threadIdx.x;
  {
    const int k = t * 4;
    float4 s1 = *(const float4*)(S1 + b * NCL + k);
    float4 s2 = *(const float4*)(S2 + b * NCL + k);
    float4 s3 = *(const float4*)(S3 + b * NCL + k);
    float c;
    c = 1.f / (s1.x + 1e-8f); c = c / (c * s2.x + 1e-8f); c = c / (c * s3.x + 1e-8f); cs[k] = c;
    c = 1.f / (s1.y + 1e-8f); c = c / (c * s2.y + 1e-8f); c = c / (c * s3.y + 1e-8f); cs[k + 1] = c;
    c = 1.f / (s1.z + 1e-8f); c = c / (c * s2.z + 1e-8f); c = c / (c * s3.z + 1e-8f); cs[k + 2] = c;
    c = 1.f / (s1.w + 1e-8f); c = c / (c * s2.w + 1e-8f); c = c / (c * s3.w + 1e-8f); cs[k + 3] = c;
    const unsigned* kp = sk + b * NCL + k;
    offs[k]     = 50.f - funkey(kp[0]) / 0.06f;
    offs[k + 1] = 50.f - funkey(kp[1]) / 0.06f;
    offs[k + 2] = 50.f - funkey(kp[2]) / 0.06f;
    offs[k + 3] = 50.f - funkey(kp[3]) / 0.06f;
  }
  __syncthreads();
  const int wave = t >> 6, lane = t & 63;
  float wsum = 0.f;
  for (int rr = wave; rr < 64; rr += 4) {
    const int row = b * HWDIM + rc * 64 + rr;
    float r3;
    {
      float r = 1.f / (T1[row] + 1e-8f);
      r = r / (r * T2[row] + 1e-8f);
      r = r / (r * T3[row] + 1e-8f);
      r3 = r;
    }
    float* p = IO + (size_t)row * NCL + lane * 16;
    float4 v0 = *(const float4*)(p);
    float4 v1 = *(const float4*)(p + 4);
    float4 v2 = *(const float4*)(p + 8);
    float4 v3 = *(const float4*)(p + 12);
    float lv[16] = {v0.x, v0.y, v0.z, v0.w, v1.x, v1.y, v1.z, v1.w,
                    v2.x, v2.y, v2.z, v2.w, v3.x, v3.y, v3.z, v3.w};
    float mx = lv[0];
#pragma unroll
    for (int j = 1; j < 16; j++) mx = fmaxf(mx, lv[j]);
    for (int o = 32; o > 0; o >>= 1) mx = fmaxf(mx, __shfl_xor(mx, o));
    const float mp = mx / 0.12f;
    float esum = 0.f, tp = 0.f, ts = 0.f;
    float tg[16];
    const float* cp = cs + lane * 16;
    const float* op = offs + lane * 16;
#pragma unroll
    for (int j = 0; j < 16; j++) {
      const float Ev = expf(lv[j] / 0.06f + op[j]);
      const float g = Ev * cp[j] * r3;
      tg[j] = g;
      const float pd = lv[j] / 0.12f;
      esum += expf(pd - mp);
      tp += g * pd;
      ts += g;
    }
    for (int o = 32; o > 0; o >>= 1) {
      esum += __shfl_xor(esum, o);
      tp += __shfl_xor(tp, o);
      ts += __shfl_xor(ts, o);
    }
    if (lane == 0) wsum += tp - (mp + logf(esum)) * ts;
    float4 w0 = {tg[0], tg[1], tg[2], tg[3]};
    float4 w1 = {tg[4], tg[5], tg[6], tg[7]};
    float4 w2 = {tg[8], tg[9], tg[10], tg[11]};
    float4 w3 = {tg[12], tg[13], tg[14], tg[15]};
    *(float4*)(p) = w0;
    *(float4*)(p + 4) = w1;
    *(float4*)(p + 8) = w2;
    *(float4*)(p + 12) = w3;
  }
  if (lane == 0) lred[wave] = wsum;
  __syncthreads();
  if (t == 0) {
    const float bl = lred[0] + lred[1] + lred[2] + lred[3];
    atomicAdd(lossout, bl * (-1.f / 32768.f));
  }
}

// ---------- launch ----------
extern "C" void kernel_launch(void* const* d_in, const int* in_sizes, int n_in,
                              void* d_out, int out_size, void* d_ws, size_t ws_size,
                              hipStream_t stream) {
  const float* x = (const float*)d_in[0];
  const float* W = (const float*)d_in[1];
  float* out = (float*)d_out;
  char* ws = (char*)d_ws;

  const size_t MiB = 1024 * 1024;
  unsigned short* Ahi = (unsigned short*)(ws);                 // 64 MiB
  unsigned short* Alo = (unsigned short*)(ws + 64 * MiB);      // 64 MiB
  unsigned short* Bhi = (unsigned short*)(ws + 128 * MiB);     // 2 MiB
  unsigned short* Blo = (unsigned short*)(ws + 130 * MiB);     // 2 MiB
  unsigned short* E   = (unsigned short*)(ws);                 // aliases Ahi (dead after GEMM)
  char* small = ws + 132 * MiB;
  unsigned* sk = (unsigned*)(small);                           // 128 KiB (zero = -inf key)
  float* S1 = (float*)(small + 128 * 1024);
  float* S2 = (float*)(small + 256 * 1024);
  float* S3 = (float*)(small + 384 * 1024);
  float* T1 = (float*)(small + 512 * 1024);
  float* T2 = (float*)(small + 640 * 1024);
  float* T3 = (float*)(small + 768 * 1024);

  float* logits = out;               // first 33554432 floats of d_out used as scratch
  float* lossp = out + 33554432;

  hipMemsetAsync(small, 0, 896 * 1024, stream);
  hipMemsetAsync(lossp, 0, 4, stream);

  normx_kernel<<<MROWS, 256, 0, stream>>>(x, Ahi, Alo);
  convw_kernel<<<NCL, 256, 0, stream>>>(W, Bhi, Blo);
  gemm_kernel<<<dim3(8, 256), 256, 0, stream>>>(Ahi, Alo, Bhi, Blo, logits);
  colmax_kernel<<<128, 256, 0, stream>>>(logits, sk);
  expcs_kernel<<<128, 256, 0, stream>>>(logits, sk, E, S1);
  rowsum_kernel<<<512, 256, 0, stream>>>(E, S1, S2, S3, 1, T1);
  colsum_kernel<<<128, 256, 0, stream>>>(E, T1, T2, T3, 1, S2);
  rowsum_kernel<<<512, 256, 0, stream>>>(E, S1, S2, S3, 2, T2);
  colsum_kernel<<<128, 256, 0, stream>>>(E, T1, T2, T3, 2, S3);
  rowsum_kernel<<<512, 256, 0, stream>>>(E, S1, S2, S3, 3, T3);
  final_kernel<<<512, 256, 0, stream>>>(logits, sk, S1, S2, S3, T1, T2, T3, lossp);
}

// Round 2
// 590.398 us; speedup vs baseline: 1.2391x; 1.2391x over previous
//
#include <hip/hip_runtime.h>
#include <cstdint>
#include <cstddef>

#define BATCH 32
#define HWDIM 1024
#define MROWS 32768   // BATCH*HWDIM
#define CDIM  1024    // feature dim
#define NCL   1024    // clusters

#define INV_TT 16.6666666f   // 1/0.06
#define INV_PT 8.33333333f   // 1/0.12

typedef __attribute__((ext_vector_type(8))) short bf16x8;
typedef __attribute__((ext_vector_type(4))) float f32x4;
typedef __attribute__((ext_vector_type(8))) unsigned short u16x8;
typedef __attribute__((ext_vector_type(4))) unsigned short u16x4;

// ---------- helpers ----------
__device__ __forceinline__ unsigned short f2bf(float f) {
  unsigned u = __float_as_uint(f);
  unsigned r = u + 0x7fffu + ((u >> 16) & 1u);   // round-to-nearest-even
  return (unsigned short)(r >> 16);
}
__device__ __forceinline__ float bf2f(unsigned short h) {
  return __uint_as_float(((unsigned)h) << 16);
}
// order-preserving float->uint key for atomicMax on floats (0 acts as -inf)
__device__ __forceinline__ unsigned fkey(float f) {
  unsigned u = __float_as_uint(f);
  return (u & 0x80000000u) ? ~u : (u | 0x80000000u);
}
__device__ __forceinline__ float funkey(unsigned k) {
  unsigned u = (k & 0x80000000u) ? (k & 0x7fffffffu) : ~k;
  return __uint_as_float(u);
}
__device__ __forceinline__ void async16(const unsigned short* g, unsigned short* l) {
  __builtin_amdgcn_global_load_lds(
      (const __attribute__((address_space(1))) unsigned int*)g,
      (__attribute__((address_space(3))) unsigned int*)l, 16, 0, 0);
}
__device__ __forceinline__ f32x4 mfma16(bf16x8 a, bf16x8 b, f32x4 c) {
  return __builtin_amdgcn_mfma_f32_16x16x32_bf16(a, b, c, 0, 0, 0);
}

// ---------- 1) normalize x rows, emit split-bf16 ----------
__global__ __launch_bounds__(256) void normx_kernel(
    const float* __restrict__ x, unsigned short* __restrict__ Ahi,
    unsigned short* __restrict__ Alo) {
  const int row = blockIdx.x;
  const int t = threadIdx.x;
  const float4 v = *(const float4*)(x + (size_t)row * CDIM + t * 4);
  float ss = v.x * v.x + v.y * v.y + v.z * v.z + v.w * v.w;
  for (int o = 32; o > 0; o >>= 1) ss += __shfl_xor(ss, o);
  __shared__ float red[4];
  const int wave = t >> 6, lane = t & 63;
  if (lane == 0) red[wave] = ss;
  __syncthreads();
  const float tot = red[0] + red[1] + red[2] + red[3];
  const float inv = 1.0f / fmaxf(sqrtf(tot), 1e-7f);
  float f0 = v.x * inv, f1 = v.y * inv, f2 = v.z * inv, f3 = v.w * inv;
  u16x4 hi, lo;
  hi[0] = f2bf(f0); lo[0] = f2bf(f0 - bf2f(hi[0]));
  hi[1] = f2bf(f1); lo[1] = f2bf(f1 - bf2f(hi[1]));
  hi[2] = f2bf(f2); lo[2] = f2bf(f2 - bf2f(hi[2]));
  hi[3] = f2bf(f3); lo[3] = f2bf(f3 - bf2f(hi[3]));
  *(u16x4*)(Ahi + (size_t)row * CDIM + t * 4) = hi;
  *(u16x4*)(Alo + (size_t)row * CDIM + t * 4) = lo;
}

// ---------- 2) split W into bf16 hi/lo ----------
__global__ __launch_bounds__(256) void convw_kernel(
    const float* __restrict__ Wm, unsigned short* __restrict__ Bhi,
    unsigned short* __restrict__ Blo) {
  const int row = blockIdx.x;
  const int t = threadIdx.x;
  const float4 v = *(const float4*)(Wm + (size_t)row * CDIM + t * 4);
  u16x4 hi, lo;
  hi[0] = f2bf(v.x); lo[0] = f2bf(v.x - bf2f(hi[0]));
  hi[1] = f2bf(v.y); lo[1] = f2bf(v.y - bf2f(hi[1]));
  hi[2] = f2bf(v.z); lo[2] = f2bf(v.z - bf2f(hi[2]));
  hi[3] = f2bf(v.w); lo[3] = f2bf(v.w - bf2f(hi[3]));
  *(u16x4*)(Bhi + (size_t)row * CDIM + t * 4) = hi;
  *(u16x4*)(Blo + (size_t)row * CDIM + t * 4) = lo;
}

// ---------- 3) split-bf16 GEMM + fused per-batch column max ----------
// 128x128 tile, BK=32, 3 MFMAs (hh + hl + lh).
// LDS chunk-rotation swizzle: row r's logical 16B k-chunk j lives at
// physical slot (j + (r>>1)) & 3 -> fragment reads become 2-way (free).
// XCD swizzle: same-m blocks land on the same XCD for A-tile L2 reuse.
__global__ __launch_bounds__(256, 4) void gemm_kernel(
    const unsigned short* __restrict__ Ahi, const unsigned short* __restrict__ Alo,
    const unsigned short* __restrict__ Bhi, const unsigned short* __restrict__ Blo,
    float* __restrict__ C, unsigned* __restrict__ sk) {
  __shared__ unsigned short sAhi[128 * 32], sAlo[128 * 32];
  __shared__ unsigned short sBhi[128 * 32], sBlo[128 * 32];
  const int l = blockIdx.x;                  // 0..2047
  const int n0 = ((l >> 3) & 7) * 128;       // 8 n-tiles
  const int m0 = (((l & 7) << 5) | (l >> 6)) * 128;  // xcd owns 32 m-tiles
  const int tid = threadIdx.x;
  const int wave = tid >> 6;
  const int lane = tid & 63;
  const int fl = lane & 15;   // fragment row/col
  const int q = lane >> 4;    // quad: k-offset q*8 (inputs), row-offset q*4 (C/D)
  const int wr = (wave >> 1) * 64;
  const int wc = (wave & 1) * 64;

  f32x4 acc[4][4];
#pragma unroll
  for (int i = 0; i < 4; i++)
#pragma unroll
    for (int j = 0; j < 4; j++) { f32x4 z = {0.f, 0.f, 0.f, 0.f}; acc[i][j] = z; }

  const int srow = lane >> 2;        // row within 16-row chunk
  const int pph = lane & 3;          // physical 16B slot this lane fills

  for (int k0 = 0; k0 < CDIM; k0 += 32) {
    __syncthreads();  // prior iteration's LDS reads complete
#pragma unroll
    for (int c = 0; c < 2; ++c) {
      const int chunk = wave * 2 + c;          // 0..7, wave-uniform
      const int r = chunk * 16 + srow;         // local row 0..127
      const int j = (pph - ((r >> 1) & 3)) & 3;  // logical k-chunk for this slot
      const size_t ga = (size_t)(m0 + r) * CDIM + k0 + j * 8;
      const size_t gb = (size_t)(n0 + r) * CDIM + k0 + j * 8;
      async16(Ahi + ga, &sAhi[chunk * 512]);
      async16(Alo + ga, &sAlo[chunk * 512]);
      async16(Bhi + gb, &sBhi[chunk * 512]);
      async16(Blo + gb, &sBlo[chunk * 512]);
    }
    __syncthreads();  // vmcnt(0) drain lands the async copies

    bf16x8 ah[4], al[4], bh[4], bl[4];
#pragma unroll
    for (int i = 0; i < 4; i++) {
      const int ra = wr + i * 16 + fl;
      const int pa = ((q + (ra >> 1)) & 3) * 8;
      ah[i] = *(const bf16x8*)&sAhi[ra * 32 + pa];
      al[i] = *(const bf16x8*)&sAlo[ra * 32 + pa];
      const int rb = wc + i * 16 + fl;
      const int pb = ((q + (rb >> 1)) & 3) * 8;
      bh[i] = *(const bf16x8*)&sBhi[rb * 32 + pb];
      bl[i] = *(const bf16x8*)&sBlo[rb * 32 + pb];
    }
#pragma unroll
    for (int i = 0; i < 4; i++)
#pragma unroll
      for (int j = 0; j < 4; j++) {
        acc[i][j] = mfma16(ah[i], bh[j], acc[i][j]);
        acc[i][j] = mfma16(ah[i], bl[j], acc[i][j]);
        acc[i][j] = mfma16(al[i], bh[j], acc[i][j]);
      }
  }

  // fused column max of this tile (per batch); tile rows are within one batch
  const int batch = m0 >> 10;
#pragma unroll
  for (int j = 0; j < 4; j++) {
    float m = -3.4e38f;
#pragma unroll
    for (int i = 0; i < 4; i++)
#pragma unroll
      for (int r = 0; r < 4; r++) m = fmaxf(m, acc[i][j][r]);
    m = fmaxf(m, __shfl_xor(m, 16));
    m = fmaxf(m, __shfl_xor(m, 32));
    if (q == 0) atomicMax(&sk[batch * NCL + n0 + wc + j * 16 + fl], fkey(m));
  }

  // epilogue: C/D layout col=lane&15, row=q*4+reg
#pragma unroll
  for (int i = 0; i < 4; i++)
#pragma unroll
    for (int j = 0; j < 4; j++)
#pragma unroll
      for (int r = 0; r < 4; r++) {
        const int gm = m0 + wr + i * 16 + q * 4 + r;
        const int gn = n0 + wc + j * 16 + fl;
        C[(size_t)gm * NCL + gn] = acc[i][j][r];
      }
}

// ---------- 4) E = exp(l/0.06 + 50 - shift) -> bf16; S1 = colsum(E) ----------
__global__ __launch_bounds__(256) void expcs_kernel(
    const float* __restrict__ L, const unsigned* __restrict__ sk,
    unsigned short* __restrict__ E, float* __restrict__ S1) {
  const int b = blockIdx.x >> 4, rc = blockIdx.x & 15, t = threadIdx.x;
  const size_t base = ((size_t)b * HWDIM + rc * 64) * NCL + t * 4;
  const unsigned* kp = sk + b * NCL + t * 4;
  const float o0 = 50.f - funkey(kp[0]) * INV_TT;
  const float o1 = 50.f - funkey(kp[1]) * INV_TT;
  const float o2 = 50.f - funkey(kp[2]) * INV_TT;
  const float o3 = 50.f - funkey(kp[3]) * INV_TT;
  float s0 = 0, s1 = 0, s2 = 0, s3 = 0;
  for (int r = 0; r < 64; ++r) {
    float4 v = *(const float4*)(L + base + (size_t)r * NCL);
    float e0 = __expf(v.x * INV_TT + o0);
    float e1 = __expf(v.y * INV_TT + o1);
    float e2 = __expf(v.z * INV_TT + o2);
    float e3 = __expf(v.w * INV_TT + o3);
    s0 += e0; s1 += e1; s2 += e2; s3 += e3;
    u16x4 ev; ev[0] = f2bf(e0); ev[1] = f2bf(e1); ev[2] = f2bf(e2); ev[3] = f2bf(e3);
    *(u16x4*)(E + base + (size_t)r * NCL) = ev;
  }
  float* d = S1 + b * NCL + t * 4;
  atomicAdd(d + 0, s0); atomicAdd(d + 1, s1);
  atomicAdd(d + 2, s2); atomicAdd(d + 3, s3);
}

// ---------- 5) fused T_i (row sums) + S_{i+1} (col sums) ----------
// c_i chained from S1..S_nS; T_i written raw; r_i chained (T1..T_{nS-1} from
// global, T_nS just computed); phase B: partial colsum E*r -> atomicAdd Sout.
__global__ __launch_bounds__(256) void fused_ts_kernel(
    const unsigned short* __restrict__ E, const float* __restrict__ S1,
    const float* __restrict__ S2, const float* __restrict__ S3,
    const float* __restrict__ T1p, const float* __restrict__ T2p, int nS,
    float* __restrict__ Tout, float* __restrict__ Sout) {
  __shared__ float cs[NCL];
  __shared__ float rr_s[64];
  const int b = blockIdx.x >> 4, rc = blockIdx.x & 15, t = threadIdx.x;
  {
    const int k = t * 4;
    float4 s1 = *(const float4*)(S1 + b * NCL + k);
    float c0 = 1.f / (s1.x + 1e-8f), c1 = 1.f / (s1.y + 1e-8f);
    float c2 = 1.f / (s1.z + 1e-8f), c3 = 1.f / (s1.w + 1e-8f);
    if (nS >= 2) {
      float4 s2 = *(const float4*)(S2 + b * NCL + k);
      c0 = c0 / (c0 * s2.x + 1e-8f); c1 = c1 / (c1 * s2.y + 1e-8f);
      c2 = c2 / (c2 * s2.z + 1e-8f); c3 = c3 / (c3 * s2.w + 1e-8f);
    }
    if (nS >= 3) {
      float4 s3 = *(const float4*)(S3 + b * NCL + k);
      c0 = c0 / (c0 * s3.x + 1e-8f); c1 = c1 / (c1 * s3.y + 1e-8f);
      c2 = c2 / (c2 * s3.z + 1e-8f); c3 = c3 / (c3 * s3.w + 1e-8f);
    }
    cs[k] = c0; cs[k + 1] = c1; cs[k + 2] = c2; cs[k + 3] = c3;
  }
  __syncthreads();
  const int wave = t >> 6, lane = t & 63;
  const int row0 = b * HWDIM + rc * 64;
  for (int rr = wave; rr < 64; rr += 4) {
    const int row = row0 + rr;
    const unsigned short* ep = E + (size_t)row * NCL + lane * 16;
    u16x8 e0 = *(const u16x8*)ep;
    u16x8 e1 = *(const u16x8*)(ep + 8);
    const float* cp = cs + lane * 16;
    float sum = 0.f;
#pragma unroll
    for (int j = 0; j < 8; j++) sum += bf2f(e0[j]) * cp[j];
#pragma unroll
    for (int j = 0; j < 8; j++) sum += bf2f(e1[j]) * cp[8 + j];
    for (int o = 32; o > 0; o >>= 1) sum += __shfl_xor(sum, o);
    if (lane == 0) {
      Tout[row] = sum;
      if (nS < 3) {
        float r;
        if (nS == 1) {
          r = 1.f / (sum + 1e-8f);
        } else {  // nS == 2
          r = 1.f / (T1p[row] + 1e-8f);
          r = r / (r * sum + 1e-8f);
        }
        rr_s[rr] = r;
      }
    }
  }
  if (nS >= 3) return;
  __syncthreads();
  float a0 = 0, a1 = 0, a2 = 0, a3 = 0;
  const unsigned short* basep = E + (size_t)row0 * NCL + t * 4;
  for (int rr = 0; rr < 64; ++rr) {
    const float rv = rr_s[rr];
    u16x4 ev = *(const u16x4*)(basep + (size_t)rr * NCL);
    a0 += bf2f(ev[0]) * rv; a1 += bf2f(ev[1]) * rv;
    a2 += bf2f(ev[2]) * rv; a3 += bf2f(ev[3]) * rv;
  }
  float* d = Sout + b * NCL + t * 4;
  atomicAdd(d + 0, a0); atomicAdd(d + 1, a1);
  atomicAdd(d + 2, a2); atomicAdd(d + 3, a3);
  (void)T2p;
}

// ---------- 6) final: assignments (in-place over logits) + loss ----------
__global__ __launch_bounds__(256) void final_kernel(
    float* __restrict__ IO, const unsigned* __restrict__ sk,
    const float* __restrict__ S1, const float* __restrict__ S2,
    const float* __restrict__ S3, const float* __restrict__ T1,
    const float* __restrict__ T2, const float* __restrict__ T3,
    float* __restrict__ lossout) {
  __shared__ float cs[NCL];
  __shared__ float offs[NCL];
  __shared__ float lred[4];
  const int b = blockIdx.x >> 4, rc = blockIdx.x & 15, t = threadIdx.x;
  {
    const int k = t * 4;
    float4 s1 = *(const float4*)(S1 + b * NCL + k);
    float4 s2 = *(const float4*)(S2 + b * NCL + k);
    float4 s3 = *(const float4*)(S3 + b * NCL + k);
    float c;
    c = 1.f / (s1.x + 1e-8f); c = c / (c * s2.x + 1e-8f); c = c / (c * s3.x + 1e-8f); cs[k] = c;
    c = 1.f / (s1.y + 1e-8f); c = c / (c * s2.y + 1e-8f); c = c / (c * s3.y + 1e-8f); cs[k + 1] = c;
    c = 1.f / (s1.z + 1e-8f); c = c / (c * s2.z + 1e-8f); c = c / (c * s3.z + 1e-8f); cs[k + 2] = c;
    c = 1.f / (s1.w + 1e-8f); c = c / (c * s2.w + 1e-8f); c = c / (c * s3.w + 1e-8f); cs[k + 3] = c;
    const unsigned* kp = sk + b * NCL + k;
    offs[k]     = 50.f - funkey(kp[0]) * INV_TT;
    offs[k + 1] = 50.f - funkey(kp[1]) * INV_TT;
    offs[k + 2] = 50.f - funkey(kp[2]) * INV_TT;
    offs[k + 3] = 50.f - funkey(kp[3]) * INV_TT;
  }
  __syncthreads();
  const int wave = t >> 6, lane = t & 63;
  float wsum = 0.f;
  for (int rr = wave; rr < 64; rr += 4) {
    const int row = b * HWDIM + rc * 64 + rr;
    float r3;
    {
      float r = 1.f / (T1[row] + 1e-8f);
      r = r / (r * T2[row] + 1e-8f);
      r = r / (r * T3[row] + 1e-8f);
      r3 = r;
    }
    float* p = IO + (size_t)row * NCL + lane * 16;
    float4 v0 = *(const float4*)(p);
    float4 v1 = *(const float4*)(p + 4);
    float4 v2 = *(const float4*)(p + 8);
    float4 v3 = *(const float4*)(p + 12);
    float lv[16] = {v0.x, v0.y, v0.z, v0.w, v1.x, v1.y, v1.z, v1.w,
                    v2.x, v2.y, v2.z, v2.w, v3.x, v3.y, v3.z, v3.w};
    float mx = lv[0];
#pragma unroll
    for (int j = 1; j < 16; j++) mx = fmaxf(mx, lv[j]);
    for (int o = 32; o > 0; o >>= 1) mx = fmaxf(mx, __shfl_xor(mx, o));
    const float mp = mx * INV_PT;
    float esum = 0.f, tp = 0.f, ts = 0.f;
    float tg[16];
    const float* cp = cs + lane * 16;
    const float* op = offs + lane * 16;
#pragma unroll
    for (int j = 0; j < 16; j++) {
      const float Ev = __expf(lv[j] * INV_TT + op[j]);
      const float g = Ev * cp[j] * r3;
      tg[j] = g;
      const float pd = lv[j] * INV_PT;
      esum += __expf(pd - mp);
      tp += g * pd;
      ts += g;
    }
    for (int o = 32; o > 0; o >>= 1) {
      esum += __shfl_xor(esum, o);
      tp += __shfl_xor(tp, o);
      ts += __shfl_xor(ts, o);
    }
    if (lane == 0) wsum += tp - (mp + logf(esum)) * ts;
    float4 w0 = {tg[0], tg[1], tg[2], tg[3]};
    float4 w1 = {tg[4], tg[5], tg[6], tg[7]};
    float4 w2 = {tg[8], tg[9], tg[10], tg[11]};
    float4 w3 = {tg[12], tg[13], tg[14], tg[15]};
    *(float4*)(p) = w0;
    *(float4*)(p + 4) = w1;
    *(float4*)(p + 8) = w2;
    *(float4*)(p + 12) = w3;
  }
  if (lane == 0) lred[wave] = wsum;
  __syncthreads();
  if (t == 0) {
    const float bl = lred[0] + lred[1] + lred[2] + lred[3];
    atomicAdd(lossout, bl * (-1.f / 32768.f));
  }
}

// ---------- launch ----------
extern "C" void kernel_launch(void* const* d_in, const int* in_sizes, int n_in,
                              void* d_out, int out_size, void* d_ws, size_t ws_size,
                              hipStream_t stream) {
  const float* x = (const float*)d_in[0];
  const float* W = (const float*)d_in[1];
  float* out = (float*)d_out;
  char* ws = (char*)d_ws;

  const size_t MiB = 1024 * 1024;
  unsigned short* Ahi = (unsigned short*)(ws);                 // 64 MiB
  unsigned short* Alo = (unsigned short*)(ws + 64 * MiB);      // 64 MiB
  unsigned short* Bhi = (unsigned short*)(ws + 128 * MiB);     // 2 MiB
  unsigned short* Blo = (unsigned short*)(ws + 130 * MiB);     // 2 MiB
  unsigned short* E   = (unsigned short*)(ws);                 // aliases Ahi (dead after GEMM)
  char* small = ws + 132 * MiB;
  unsigned* sk = (unsigned*)(small);                           // 128 KiB (zero = -inf key)
  float* S1 = (float*)(small + 128 * 1024);
  float* S2 = (float*)(small + 256 * 1024);
  float* S3 = (float*)(small + 384 * 1024);
  float* T1 = (float*)(small + 512 * 1024);
  float* T2 = (float*)(small + 640 * 1024);
  float* T3 = (float*)(small + 768 * 1024);

  float* logits = out;               // first 33554432 floats of d_out used as scratch
  float* lossp = out + 33554432;

  hipMemsetAsync(small, 0, 896 * 1024, stream);
  hipMemsetAsync(lossp, 0, 4, stream);

  normx_kernel<<<MROWS, 256, 0, stream>>>(x, Ahi, Alo);
  convw_kernel<<<NCL, 256, 0, stream>>>(W, Bhi, Blo);
  gemm_kernel<<<2048, 256, 0, stream>>>(Ahi, Alo, Bhi, Blo, logits, sk);
  expcs_kernel<<<512, 256, 0, stream>>>(logits, sk, E, S1);
  fused_ts_kernel<<<512, 256, 0, stream>>>(E, S1, S2, S3, T1, T2, 1, T1, S2);
  fused_ts_kernel<<<512, 256, 0, stream>>>(E, S1, S2, S3, T1, T2, 2, T2, S3);
  fused_ts_kernel<<<512, 256, 0, stream>>>(E, S1, S2, S3, T1, T2, 3, T3, nullptr);
  final_kernel<<<512, 256, 0, stream>>>(logits, sk, S1, S2, S3, T1, T2, T3, lossp);
}